// Round 10
// baseline (600.442 us; speedup 1.0000x reference)
//
#include <hip/hip_runtime.h>
#include <hip/hip_bf16.h>

#define NN 8192
#define DD 256
#define BM 128
#define BN 128
#define BK 32

typedef __bf16 bf16x8 __attribute__((ext_vector_type(8)));
typedef float f32x4 __attribute__((ext_vector_type(4)));

__device__ inline void gload_lds16(const void* g, void* l) {
  __builtin_amdgcn_global_load_lds(
      (const __attribute__((address_space(1))) void*)g,
      (__attribute__((address_space(3))) void*)l, 16, 0, 0);
}

// ---------------- prep: rnorm + bf16 hi/lo split ----------------
__global__ __launch_bounds__(256) void prep_kernel(
    const float* __restrict__ Z,
    __hip_bfloat16* __restrict__ Zhi,
    __hip_bfloat16* __restrict__ Zlo,
    float* __restrict__ rnorm) {
  const int gtid = blockIdx.x * 256 + threadIdx.x;
  const int row  = gtid >> 6;          // one wave per row
  const int lane = threadIdx.x & 63;
  if (row >= NN) return;

  const float4 v = reinterpret_cast<const float4*>(Z + (size_t)row * DD)[lane];
  float ss = v.x * v.x + v.y * v.y + v.z * v.z + v.w * v.w;
#pragma unroll
  for (int off = 32; off > 0; off >>= 1) ss += __shfl_xor(ss, off);
  if (lane == 0) rnorm[row] = 1.0f / fmaxf(sqrtf(ss), 1e-8f);

  float f[4] = {v.x, v.y, v.z, v.w};
  unsigned short hi[4], lo[4];
#pragma unroll
  for (int i = 0; i < 4; ++i) {
    __hip_bfloat16 h = __float2bfloat16(f[i]);
    float hf = __bfloat162float(h);
    __hip_bfloat16 l = __float2bfloat16(f[i] - hf);
    hi[i] = *reinterpret_cast<unsigned short*>(&h);
    lo[i] = *reinterpret_cast<unsigned short*>(&l);
  }
  ushort4 hv = make_ushort4(hi[0], hi[1], hi[2], hi[3]);
  ushort4 lv = make_ushort4(lo[0], lo[1], lo[2], lo[3]);
  reinterpret_cast<ushort4*>(Zhi + (size_t)row * DD)[lane] = hv;
  reinterpret_cast<ushort4*>(Zlo + (size_t)row * DD)[lane] = lv;
}

// LDS: staging (32KB) + wave-private half-tile tbuf (33.8KB) + dbuf'd
// norm/batch (4KB). ~69KB -> 2 blocks/CU.
struct __attribute__((aligned(16))) SharedT {
  __hip_bfloat16 Ah[BM * BK];
  __hip_bfloat16 Al[BM * BK];
  __hip_bfloat16 Bh[BN * BK];
  __hip_bfloat16 Bl[BN * BK];
  float tb[4][32][66];       // per-wave 32x64 (+2 pad): all patterns <=2-way
  float sRn[2][2][128];      // [buf][A=0/B=1][row]
  int   sBt[2][2][128];
};

// ---- 4-tile pipelined Gram: tile t's stores woven into tile t+1's K-loop ---
__global__ __launch_bounds__(256, 2) void gram_kernel(
    const __hip_bfloat16* __restrict__ Zhi,
    const __hip_bfloat16* __restrict__ Zlo,
    const float* __restrict__ rnorm,
    const int* __restrict__ batch,
    float* __restrict__ outA,
    float* __restrict__ outS) {
  __shared__ SharedT sh;

  const int tid  = threadIdx.x;
  const int lane = tid & 63;
  const int wid  = tid >> 6;
  const int wr   = wid >> 1;   // 2x2 wave grid, wave owns 64x64
  const int wc   = wid & 1;
  const int lr   = lane >> 4;
  const int lc   = lane & 15;

  // XCD-bijective tile-group id (520 = 8*65); 4 consecutive tiles per block
  const int b = blockIdx.x;
  const int s = (b & 7) * 65 + (b >> 3);

  int prow0 = 0, pcol0 = 0;
  bool pmir = false;

  f32x4 accA[4][4], accB[4][4];
  float* T = &sh.tb[wid][0][0];   // [32][66]

  auto decode = [](int idx, int& r0, int& c0, bool& mir) {
    int bc = (int)((sqrtf(8.0f * (float)idx + 1.0f) - 1.0f) * 0.5f);
    while ((bc + 1) * (bc + 2) / 2 <= idx) ++bc;
    while (bc * (bc + 1) / 2 > idx) --bc;
    const int br = idx - bc * (bc + 1) / 2;
    r0 = br * BM; c0 = bc * BN; mir = (br != bc);
  };

  // one kt-slice (1/8) of the previous tile's epilogue
  auto store_chunk = [&](int kt, const f32x4 (&prv)[4][4], int pbuf) {
    const int h  = kt >> 2;            // half 0: m{0,1}; half 1: m{2,3}
    const int ph = kt & 3;
    const int rbase = wr * 64 + h * 32;
    if (ph == 0) {                     // dump this half into wave-private T
#pragma unroll
      for (int mm = 0; mm < 2; ++mm)
#pragma unroll
        for (int n = 0; n < 4; ++n)
#pragma unroll
          for (int j = 0; j < 4; ++j)
            T[(mm * 16 + lr * 4 + j) * 66 + n * 16 + lc] = prv[h * 2 + mm][n][j];
    }
    if (ph < 2) {                      // A-direct: 16 rows, 256B per instr
#pragma unroll
      for (int r0i = 0; r0i < 16; ++r0i) {
        const int r  = ph * 16 + r0i;
        const int rl = rbase + r;
        const int cl = wc * 64 + lane;
        const float g = T[r * 66 + lane];
        const float a = __builtin_amdgcn_rcpf(1.0f + __expf(-g));
        const float sv = (sh.sBt[pbuf][0][rl] == sh.sBt[pbuf][1][cl])
                             ? g * sh.sRn[pbuf][0][rl] * sh.sRn[pbuf][1][cl]
                             : 0.0f;
        const size_t o = (size_t)(prow0 + rl) * NN + (pcol0 + cl);
        outA[o] = a;
        outS[o] = sv;
      }
    } else if (pmir) {                 // mirror: 2x128B full lines per instr
#pragma unroll
      for (int i0 = 0; i0 < 16; ++i0) {
        const int i  = (ph - 2) * 16 + i0;
        const int c  = i * 2 + (lane >> 5);
        const int r  = lane & 31;
        const int rl = rbase + r;       // orig row  = mirror col
        const int cl = wc * 64 + c;     // orig col  = mirror row
        const float g = T[r * 66 + c];
        const float a = __builtin_amdgcn_rcpf(1.0f + __expf(-g));
        const float sv = (sh.sBt[pbuf][0][rl] == sh.sBt[pbuf][1][cl])
                             ? g * sh.sRn[pbuf][0][rl] * sh.sRn[pbuf][1][cl]
                             : 0.0f;
        const size_t o = (size_t)(pcol0 + cl) * NN + (prow0 + rl);
        outA[o] = a;
        outS[o] = sv;
      }
    }
  };

  auto tile_step = [&](f32x4 (&cur)[4][4], const f32x4 (&prv)[4][4], int idx,
                       bool do_store, int cbuf, int pbuf) {
    int row0, col0; bool mir;
    decode(idx, row0, col0, mir);
    // load THIS tile's norm/batch (consumed by stores during NEXT step)
    if (tid < 128) {
      sh.sRn[cbuf][0][tid] = rnorm[row0 + tid];
      sh.sBt[cbuf][0][tid] = batch[row0 + tid];
    } else {
      const int t2 = tid - 128;
      sh.sRn[cbuf][1][t2] = rnorm[col0 + t2];
      sh.sBt[cbuf][1][t2] = batch[col0 + t2];
    }
#pragma unroll
    for (int m = 0; m < 4; ++m)
#pragma unroll
      for (int n = 0; n < 4; ++n) cur[m][n] = (f32x4){0, 0, 0, 0};

#pragma unroll
    for (int kt = 0; kt < DD / BK; ++kt) {
      const int k0 = kt * BK;
#pragma unroll
      for (int c = 0; c < 2; ++c) {
        const int ci  = c * 256 + tid;
        const int r   = ci >> 2;
        const int ch  = ci & 3;
        const int chg = ch ^ ((r >> 1) & 3);     // swizzle involution
        const int base = (c * 256 + wid * 64) * 16;
        const size_t ga = (size_t)(row0 + r) * DD + k0 + chg * 8;
        const size_t gb = (size_t)(col0 + r) * DD + k0 + chg * 8;
        gload_lds16(Zhi + ga, (char*)sh.Ah + base);
        gload_lds16(Zlo + ga, (char*)sh.Al + base);
        gload_lds16(Zhi + gb, (char*)sh.Bh + base);
        gload_lds16(Zlo + gb, (char*)sh.Bl + base);
      }
      __syncthreads();   // staging ready

      if (do_store) store_chunk(kt, prv, pbuf);   // retires under MFMA below

      bf16x8 fa[4], fb[4], ft[4];
#pragma unroll
      for (int m = 0; m < 4; ++m) {
        const int rA = wr * 64 + m * 16 + lc;
        const int off = rA * BK + ((lr ^ ((rA >> 1) & 3)) << 3);
        fa[m] = *reinterpret_cast<const bf16x8*>(&sh.Ah[off]);
      }
#pragma unroll
      for (int n = 0; n < 4; ++n) {
        const int rB = wc * 64 + n * 16 + lc;
        const int off = rB * BK + ((lr ^ ((rB >> 1) & 3)) << 3);
        fb[n] = *reinterpret_cast<const bf16x8*>(&sh.Bh[off]);
      }
#pragma unroll
      for (int m = 0; m < 4; ++m)
#pragma unroll
        for (int n = 0; n < 4; ++n)
          cur[m][n] = __builtin_amdgcn_mfma_f32_16x16x32_bf16(fa[m], fb[n], cur[m][n], 0, 0, 0);
#pragma unroll
      for (int m = 0; m < 4; ++m) {
        const int rA = wr * 64 + m * 16 + lc;
        const int off = rA * BK + ((lr ^ ((rA >> 1) & 3)) << 3);
        ft[m] = *reinterpret_cast<const bf16x8*>(&sh.Al[off]);
      }
#pragma unroll
      for (int m = 0; m < 4; ++m)
#pragma unroll
        for (int n = 0; n < 4; ++n)
          cur[m][n] = __builtin_amdgcn_mfma_f32_16x16x32_bf16(ft[m], fb[n], cur[m][n], 0, 0, 0);
#pragma unroll
      for (int n = 0; n < 4; ++n) {
        const int rB = wc * 64 + n * 16 + lc;
        const int off = rB * BK + ((lr ^ ((rB >> 1) & 3)) << 3);
        fb[n] = *reinterpret_cast<const bf16x8*>(&sh.Bl[off]);
      }
#pragma unroll
      for (int m = 0; m < 4; ++m)
#pragma unroll
        for (int n = 0; n < 4; ++n)
          cur[m][n] = __builtin_amdgcn_mfma_f32_16x16x32_bf16(fa[m], fb[n], cur[m][n], 0, 0, 0);
      __syncthreads();   // staging consumed; store chunk drained
    }
    prow0 = row0; pcol0 = col0; pmir = mir;   // become "previous" tile
  };

  tile_step(accA, accB, 4 * s + 0, false, 0, 1);  // prv unused
  tile_step(accB, accA, 4 * s + 1, true,  1, 0);  // stores tile0 (buf0)
  tile_step(accA, accB, 4 * s + 2, true,  0, 1);  // stores tile1 (buf1)
  tile_step(accB, accA, 4 * s + 3, true,  1, 0);  // stores tile2 (buf0)

  // tail: drain tile3 (accB, buf1); wave-private T, no barriers needed
#pragma unroll
  for (int kt = 0; kt < 8; ++kt) store_chunk(kt, accB, 1);
}

extern "C" void kernel_launch(void* const* d_in, const int* in_sizes, int n_in,
                              void* d_out, int out_size, void* d_ws, size_t ws_size,
                              hipStream_t stream) {
  const float* Z     = (const float*)d_in[0];
  const int*   batch = (const int*)d_in[1];
  float* out = (float*)d_out;

  __hip_bfloat16* Zhi = (__hip_bfloat16*)d_ws;
  __hip_bfloat16* Zlo = Zhi + (size_t)NN * DD;
  float* rnorm = (float*)(Zlo + (size_t)NN * DD);

  prep_kernel<<<NN / 4, 256, 0, stream>>>(Z, Zhi, Zlo, rnorm);

  // 2080 triangular tiles, 4 per block -> 520 blocks
  gram_kernel<<<dim3(520), 256, 0, stream>>>(Zhi, Zlo, rnorm, batch, out,
                                             out + (size_t)NN * NN);
}

// Round 11
// 141.873 us; speedup vs baseline: 4.2323x; 4.2323x over previous
//
#include <hip/hip_runtime.h>
#include <hip/hip_bf16.h>

#define NN 8192
#define DD 256
#define BM 128
#define BN 128
#define BK 32

typedef __bf16 bf16x8 __attribute__((ext_vector_type(8)));
typedef float f32x4 __attribute__((ext_vector_type(4)));

__device__ inline void gload_lds16(const void* g, void* l) {
  __builtin_amdgcn_global_load_lds(
      (const __attribute__((address_space(1))) void*)g,
      (__attribute__((address_space(3))) void*)l, 16, 0, 0);
}

// ---------------- prep: rnorm + bf16 hi/lo split ----------------
__global__ __launch_bounds__(256) void prep_kernel(
    const float* __restrict__ Z,
    __hip_bfloat16* __restrict__ Zhi,
    __hip_bfloat16* __restrict__ Zlo,
    float* __restrict__ rnorm) {
  const int gtid = blockIdx.x * 256 + threadIdx.x;
  const int row  = gtid >> 6;          // one wave per row
  const int lane = threadIdx.x & 63;
  if (row >= NN) return;

  const float4 v = reinterpret_cast<const float4*>(Z + (size_t)row * DD)[lane];
  float ss = v.x * v.x + v.y * v.y + v.z * v.z + v.w * v.w;
#pragma unroll
  for (int off = 32; off > 0; off >>= 1) ss += __shfl_xor(ss, off);
  if (lane == 0) rnorm[row] = 1.0f / fmaxf(sqrtf(ss), 1e-8f);

  float f[4] = {v.x, v.y, v.z, v.w};
  unsigned short hi[4], lo[4];
#pragma unroll
  for (int i = 0; i < 4; ++i) {
    __hip_bfloat16 h = __float2bfloat16(f[i]);
    float hf = __bfloat162float(h);
    __hip_bfloat16 l = __float2bfloat16(f[i] - hf);
    hi[i] = *reinterpret_cast<unsigned short*>(&h);
    lo[i] = *reinterpret_cast<unsigned short*>(&l);
  }
  ushort4 hv = make_ushort4(hi[0], hi[1], hi[2], hi[3]);
  ushort4 lv = make_ushort4(lo[0], lo[1], lo[2], lo[3]);
  reinterpret_cast<ushort4*>(Zhi + (size_t)row * DD)[lane] = hv;
  reinterpret_cast<ushort4*>(Zlo + (size_t)row * DD)[lane] = lv;
}

// LDS: K-loop staging tiles union'd with 4 wave-private HALF-tile (32-row)
// transpose buffers. Pad 66: dump/row-read/col-read all <=2-way (free).
struct __attribute__((aligned(16))) SharedT {
  union {
    struct {
      __hip_bfloat16 Ah[BM * BK];
      __hip_bfloat16 Al[BM * BK];
      __hip_bfloat16 Bh[BN * BK];
      __hip_bfloat16 Bl[BN * BK];
    } t;                        // 32 KB
    float tbuf[4][32][66];      // 33.8 KB, per-wave 32x64 (+2 pad)
  };
};

// ------ upper-tri Gram GEMM + barrier-free nontemporal dual epilogue --------
__global__ __launch_bounds__(256, 2) void gram_kernel(
    const __hip_bfloat16* __restrict__ Zhi,
    const __hip_bfloat16* __restrict__ Zlo,
    const float* __restrict__ rnorm,
    const int* __restrict__ batch,
    float* __restrict__ outA,
    float* __restrict__ outS) {
  __shared__ SharedT sh;
  __shared__ float sRnA[BM];
  __shared__ float sRnB[BN];
  __shared__ int   sBtA[BM];
  __shared__ int   sBtB[BN];

  const int tid  = threadIdx.x;
  const int lane = tid & 63;
  const int wid  = tid >> 6;
  const int wr   = wid >> 1;   // 2x2 wave grid, each wave 64x64
  const int wc   = wid & 1;

  // XCD-aware swizzle (2080 % 8 == 0 -> bijective)
  const int nb  = NN / BM;                 // 64
  const int nwg = nb * (nb + 1) / 2;       // 2080
  const int bid = blockIdx.x;
  const int idx = (bid & 7) * (nwg >> 3) + (bid >> 3);

  // triangular decode: idx -> (brow <= bcol)
  int bcol = (int)((sqrtf(8.0f * (float)idx + 1.0f) - 1.0f) * 0.5f);
  while ((bcol + 1) * (bcol + 2) / 2 <= idx) ++bcol;
  while (bcol * (bcol + 1) / 2 > idx) --bcol;
  const int brow = idx - bcol * (bcol + 1) / 2;
  const int row0 = brow * BM, col0 = bcol * BN;

  if (tid < 128) {
    sRnA[tid] = rnorm[row0 + tid];
    sBtA[tid] = batch[row0 + tid];
  } else {
    const int t = tid - 128;
    sRnB[t] = rnorm[col0 + t];
    sBtB[t] = batch[col0 + t];
  }

  f32x4 acc[4][4] = {};

  const int lr = lane >> 4;   // 0..3  (k-chunk)
  const int lc = lane & 15;   // 0..15 (row within fragment)

  for (int kt = 0; kt < DD / BK; ++kt) {
    const int k0 = kt * BK;
    // stage 4 tiles of 128x32 bf16, XOR-swizzled on the GLOBAL side
#pragma unroll
    for (int c = 0; c < 2; ++c) {
      const int ci  = c * 256 + tid;            // 16B-chunk index [0,512)
      const int r   = ci >> 2;                  // tile-local row
      const int ch  = ci & 3;
      const int chg = ch ^ ((r >> 1) & 3);      // swizzled source chunk
      const int base = (c * 256 + wid * 64) * 16;  // wave-uniform LDS byte base
      const size_t ga = (size_t)(row0 + r) * DD + k0 + chg * 8;
      const size_t gb = (size_t)(col0 + r) * DD + k0 + chg * 8;
      gload_lds16(Zhi + ga, (char*)sh.t.Ah + base);
      gload_lds16(Zlo + ga, (char*)sh.t.Al + base);
      gload_lds16(Zhi + gb, (char*)sh.t.Bh + base);
      gload_lds16(Zlo + gb, (char*)sh.t.Bl + base);
    }
    __syncthreads();   // drains vmcnt before any wave reads LDS

    // fragment-staged MFMA: peak live = fa+fb+ft = 48 VGPR
    bf16x8 fa[4], fb[4], ft[4];
#pragma unroll
    for (int m = 0; m < 4; ++m) {
      const int rA = wr * 64 + m * 16 + lc;
      const int off = rA * BK + ((lr ^ ((rA >> 1) & 3)) << 3);
      fa[m] = *reinterpret_cast<const bf16x8*>(&sh.t.Ah[off]);
    }
#pragma unroll
    for (int n = 0; n < 4; ++n) {
      const int rB = wc * 64 + n * 16 + lc;
      const int off = rB * BK + ((lr ^ ((rB >> 1) & 3)) << 3);
      fb[n] = *reinterpret_cast<const bf16x8*>(&sh.t.Bh[off]);
    }
#pragma unroll
    for (int m = 0; m < 4; ++m)
#pragma unroll
      for (int n = 0; n < 4; ++n)
        acc[m][n] = __builtin_amdgcn_mfma_f32_16x16x32_bf16(fa[m], fb[n], acc[m][n], 0, 0, 0);
#pragma unroll
    for (int m = 0; m < 4; ++m) {
      const int rA = wr * 64 + m * 16 + lc;
      const int off = rA * BK + ((lr ^ ((rA >> 1) & 3)) << 3);
      ft[m] = *reinterpret_cast<const bf16x8*>(&sh.t.Al[off]);
    }
#pragma unroll
    for (int m = 0; m < 4; ++m)
#pragma unroll
      for (int n = 0; n < 4; ++n)
        acc[m][n] = __builtin_amdgcn_mfma_f32_16x16x32_bf16(ft[m], fb[n], acc[m][n], 0, 0, 0);
#pragma unroll
    for (int n = 0; n < 4; ++n) {
      const int rB = wc * 64 + n * 16 + lc;
      const int off = rB * BK + ((lr ^ ((rB >> 1) & 3)) << 3);
      fb[n] = *reinterpret_cast<const bf16x8*>(&sh.t.Bl[off]);
    }
#pragma unroll
    for (int m = 0; m < 4; ++m)
#pragma unroll
      for (int n = 0; n < 4; ++n)
        acc[m][n] = __builtin_amdgcn_mfma_f32_16x16x32_bf16(fa[m], fb[n], acc[m][n], 0, 0, 0);
    __syncthreads();   // last one also protects tbuf overlay below
  }

  const bool mirror = (brow != bcol);

  // Barrier-free epilogue: 2 passes of 32 rows (two m-steps each) through the
  // wave-private tbuf. All stores NONTEMPORAL: stream past L2, keep Z resident.
  float* T = &sh.tbuf[wid][0][0];   // [32][66] f32

  for (int p = 0; p < 2; ++p) {
    // dump 32x64 (acc m = 2p, 2p+1); bank multiplicity <=2 (free)
#pragma unroll
    for (int mm = 0; mm < 2; ++mm) {
#pragma unroll
      for (int n = 0; n < 4; ++n)
#pragma unroll
        for (int j = 0; j < 4; ++j)
          T[(mm * 16 + lr * 4 + j) * 66 + n * 16 + lc] = acc[p * 2 + mm][n][j];
    }
    // (same-wave ds_write->ds_read: compiler inserts lgkmcnt; no barrier)

    // phase A: 256B-contiguous row stores (unroll capped: bound VGPR spike)
#pragma unroll 8
    for (int r = 0; r < 32; ++r) {
      const int rl = wr * 64 + p * 32 + r;   // block-local row
      const int cl = wc * 64 + lane;         // block-local col
      const float g = T[r * 66 + lane];
      const float a = __builtin_amdgcn_rcpf(1.0f + __expf(-g));
      const float s = (sBtA[rl] == sBtB[cl]) ? g * sRnA[rl] * sRnB[cl] : 0.0f;
      const size_t o = (size_t)(row0 + rl) * NN + (col0 + cl);
      __builtin_nontemporal_store(a, outA + o);
      __builtin_nontemporal_store(s, outS + o);
    }

    // phase B: mirrored; each 32-lane half writes one aligned 128B line
    if (mirror) {
#pragma unroll 8
      for (int i = 0; i < 32; ++i) {
        const int c  = i * 2 + (lane >> 5);  // 0..63 wave-local mirror row
        const int r  = lane & 31;            // 0..31 orig row within pass
        const int rl = wr * 64 + p * 32 + r;
        const int cl = wc * 64 + c;
        const float g = T[r * 66 + c];
        const float a = __builtin_amdgcn_rcpf(1.0f + __expf(-g));
        const float s = (sBtB[cl] == sBtA[rl]) ? g * sRnB[cl] * sRnA[rl] : 0.0f;
        const size_t o = (size_t)(col0 + cl) * NN + (row0 + rl);
        __builtin_nontemporal_store(a, outA + o);
        __builtin_nontemporal_store(s, outS + o);
      }
    }
  }
}

extern "C" void kernel_launch(void* const* d_in, const int* in_sizes, int n_in,
                              void* d_out, int out_size, void* d_ws, size_t ws_size,
                              hipStream_t stream) {
  const float* Z     = (const float*)d_in[0];
  const int*   batch = (const int*)d_in[1];
  float* out = (float*)d_out;

  __hip_bfloat16* Zhi = (__hip_bfloat16*)d_ws;
  __hip_bfloat16* Zlo = Zhi + (size_t)NN * DD;
  float* rnorm = (float*)(Zlo + (size_t)NN * DD);

  prep_kernel<<<NN / 4, 256, 0, stream>>>(Z, Zhi, Zlo, rnorm);

  const int nb = NN / BM;                 // 64
  const int nblocks = nb * (nb + 1) / 2;  // 2080
  gram_kernel<<<dim3(nblocks), 256, 0, stream>>>(Zhi, Zlo, rnorm, batch, out,
                                                 out + (size_t)NN * NN);
}